// Round 7
// baseline (129.862 us; speedup 1.0000x reference)
//
#include <hip/hip_runtime.h>

typedef short bf16x8 __attribute__((ext_vector_type(8)));
typedef float f32x4 __attribute__((ext_vector_type(4)));

#define D 128
#define NBLK 256                            // (dist 2) x (m 64) x (xh 2)
#define INV_COUNT 5.9604644775390625e-08f   // 1 / (64*512*512)

__device__ __forceinline__ unsigned short f2bf(float f) {
    unsigned u = __float_as_uint(f);
    u += 0x7FFFu + ((u >> 16) & 1u);        // round-to-nearest-even
    return (unsigned short)(u >> 16);
}
__device__ __forceinline__ float bf2f(unsigned short h) {
    return __uint_as_float(((unsigned)h) << 16);
}

// Per-thread prep of 16 row elements: fp32 loads -> bf16 (RNE) -> packed
// uint4 pair + sum-of-squares (+ column-sum accumulate). All indices static.
__device__ __forceinline__ void prep16(const float* ep, const float* up,
                                       const float* sp, uint4& q0, uint4& q1,
                                       float& ss, float* cs)
{
    unsigned pk[8];
    ss = 0.f;
    #pragma unroll
    for (int j = 0; j < 4; ++j) {
        float4 e = ((const float4*)ep)[j];
        float4 u = ((const float4*)up)[j];
        float4 s = ((const float4*)sp)[j];
        unsigned short h0 = f2bf(fmaf(s.x, e.x, u.x));
        unsigned short h1 = f2bf(fmaf(s.y, e.y, u.y));
        unsigned short h2 = f2bf(fmaf(s.z, e.z, u.z));
        unsigned short h3 = f2bf(fmaf(s.w, e.w, u.w));
        float f0 = bf2f(h0), f1 = bf2f(h1), f2 = bf2f(h2), f3 = bf2f(h3);
        ss += f0 * f0 + f1 * f1 + f2 * f2 + f3 * f3;
        cs[j * 4 + 0] += f0; cs[j * 4 + 1] += f1;
        cs[j * 4 + 2] += f2; cs[j * 4 + 3] += f3;
        pk[j * 2 + 0] = (unsigned)h0 | ((unsigned)h1 << 16);
        pk[j * 2 + 1] = (unsigned)h2 | ((unsigned)h3 << 16);
    }
    q0 = make_uint4(pk[0], pk[1], pk[2], pk[3]);
    q1 = make_uint4(pk[4], pk[5], pk[6], pk[7]);
}

// MONO kernel: 256 blocks x 512 threads, ~36 KB LDS. Block (dist,m,xh):
//  - x side (X_B rows xh*256..+256) prepped from mu/sigma/epsB in 4 passes
//    of 64 rows through Ys[0]; each wave picks its A fragments (32 rows x
//    K128) into registers. LDS layout = the HW-verified swizzle:
//    row r slot g^(r&7) holds granule g; frag read (kk*4+quad)^(r&7).
//  - y side (X_A or X_C, 512 rows) streamed in 8 chunks of 64 rows through
//    a double buffer: chunk c+1 loads+cvt (registers) overlap chunk c MFMA;
//    ds_write happens between the two barriers. No global intermediate.
//  - xh==0 blocks fold 512*sum|y|^2 into lsum and accumulate y column sums
//    (pos term closed form) from the prep registers.
__global__ __launch_bounds__(512) void mono_kernel(
    const float* __restrict__ mu, const float* __restrict__ sigma,
    const float* __restrict__ epsA, const float* __restrict__ epsB,
    const float* __restrict__ epsC,
    float* __restrict__ pslots, float* __restrict__ Scol)
{
    __shared__ unsigned short Ys[2][64 * 128];   // 32 KB dbuf (x transit + y stream)
    __shared__ float ssx_s[256];
    __shared__ float ssy_s[512];
    __shared__ float red[8];

    const int bx = blockIdx.x;
    const int t  = threadIdx.x;
    const int wave = t >> 6, lane = t & 63;

    const int xcd = bx & 7;
    const int mh  = (bx >> 3) & 7;
    const int m   = xcd + mh * 8;             // m % 8 == xcd
    const int q   = bx >> 6;
    const int dist = q & 1;                   // 0 -> dBA (y=A), 1 -> dBC (y=C)
    const int xh   = q >> 1;                  // which 256-row half of X_B
    const int gy   = dist ? 2 : 0;

    const float* epsY = (dist ? epsC : epsA) + (size_t)m * 512 * D;
    const float* epsX = epsB + ((size_t)m * 512 + xh * 256) * D;
    const float* muY  = mu    + (size_t)gy * 512 * D;
    const float* sgY  = sigma + (size_t)gy * 512 * D;
    const float* muX  = mu    + (size_t)(512 + xh * 256) * D;
    const float* sgX  = sigma + (size_t)(512 + xh * 256) * D;

    const int tr = t >> 3;                    // row within 64-row pass/chunk
    const int tc = t & 7;                     // 16-elem col segment
    const int coff = tc * 16;
    const int l15 = lane & 15, quad = lane >> 4;

    float cs[16];
    #pragma unroll
    for (int j = 0; j < 16; ++j) cs[j] = 0.f;
    float csx[16];                            // x-prep sink (unused for pos)
    #pragma unroll
    for (int j = 0; j < 16; ++j) csx[j] = 0.f;

    float lsum = 0.f;

    // -------- x prep: 4 passes of 64 rows through Ys[0]; waves pick aF ----
    bf16x8 aF[4][2];                          // [kk][fr]: 32 x-rows x K128
    for (int p = 0; p < 4; ++p) {
        const size_t n = (size_t)(p * 64 + tr);
        uint4 q0, q1; float ss;
        prep16(epsX + n * D + coff, muX + n * D + coff, sgX + n * D + coff,
               q0, q1, ss, csx);
        unsigned short* rowp = &Ys[0][tr * 128];
        *(uint4*)&rowp[((tc * 2)     ^ (tr & 7)) * 8] = q0;
        *(uint4*)&rowp[((tc * 2 + 1) ^ (tr & 7)) * 8] = q1;
        ss += __shfl_xor(ss, 1); ss += __shfl_xor(ss, 2); ss += __shfl_xor(ss, 4);
        if (tc == 0) ssx_s[p * 64 + tr] = ss;
        __syncthreads();
        if ((wave >> 1) == p) {
            #pragma unroll
            for (int kk = 0; kk < 4; kk++)
                #pragma unroll
                for (int fr = 0; fr < 2; fr++) {
                    const int row = (wave & 1) * 32 + fr * 16 + l15;
                    aF[kk][fr] = *(const bf16x8*)&Ys[0][row * 128 +
                                  (((kk * 4 + quad) ^ (row & 7)) * 8)];
                }
        }
        __syncthreads();
    }

    // -------- y chunk 0 prep into Ys[0] --------
    {
        const size_t n = (size_t)tr;
        uint4 q0, q1; float ss;
        prep16(epsY + n * D + coff, muY + n * D + coff, sgY + n * D + coff,
               q0, q1, ss, cs);
        unsigned short* rowp = &Ys[0][tr * 128];
        *(uint4*)&rowp[((tc * 2)     ^ (tr & 7)) * 8] = q0;
        *(uint4*)&rowp[((tc * 2 + 1) ^ (tr & 7)) * 8] = q1;
        ss += __shfl_xor(ss, 1); ss += __shfl_xor(ss, 2); ss += __shfl_xor(ss, 4);
        if (tc == 0) { ssy_s[tr] = ss; if (xh == 0) lsum += 512.f * ss; }
        __syncthreads();
    }

    f32x4 acc[2][4] = {};

    // -------- main loop: 8 chunks of 64 y rows --------
    #pragma unroll 1
    for (int c = 0; c < 8; ++c) {
        const unsigned short* bb = (c & 1) ? Ys[1] : Ys[0];
        unsigned short*       wb = (c & 1) ? Ys[0] : Ys[1];

        // prep chunk c+1 in registers (loads issue now, overlap MFMA below)
        uint4 q0n, q1n; float ssn = 0.f;
        if (c < 7) {
            const size_t n = (size_t)((c + 1) * 64 + tr);
            prep16(epsY + n * D + coff, muY + n * D + coff, sgY + n * D + coff,
                   q0n, q1n, ssn, cs);
        }

        // MFMA on chunk c
        #pragma unroll
        for (int kk = 0; kk < 4; kk++) {
            bf16x8 bfr[4];
            #pragma unroll
            for (int fc = 0; fc < 4; fc++) {
                const int row = fc * 16 + l15;
                bfr[fc] = *(const bf16x8*)&bb[row * 128 +
                            (((kk * 4 + quad) ^ (row & 7)) * 8)];
            }
            #pragma unroll
            for (int fr = 0; fr < 2; fr++)
                #pragma unroll
                for (int fc = 0; fc < 4; fc++)
                    acc[fr][fc] = __builtin_amdgcn_mfma_f32_16x16x32_bf16(
                        aF[kk][fr], bfr[fc], acc[fr][fc], 0, 0, 0);
        }

        // epilogue chunk c; C layout: col=lane&15, row=quad*4+ii
        #pragma unroll
        for (int fc = 0; fc < 4; fc++) {
            float y2 = ssy_s[c * 64 + fc * 16 + l15];
            #pragma unroll
            for (int fr = 0; fr < 2; fr++) {
                float d2v[4];
                #pragma unroll
                for (int ii = 0; ii < 4; ii++) {
                    float x2 = ssx_s[wave * 32 + fr * 16 + quad * 4 + ii];
                    d2v[ii] = fmaf(-2.f, acc[fr][fc][ii], x2 + y2);
                }
                float mn = fminf(fminf(d2v[0], d2v[1]), fminf(d2v[2], d2v[3]));
                if (__any(mn < 4.f)) {        // relu(M-d) nonzero is rare
                    #pragma unroll
                    for (int ii = 0; ii < 4; ii++) {
                        if (d2v[ii] < 4.f) {
                            float td = 2.f - sqrtf(fmaxf(d2v[ii], 1e-12f));
                            lsum += td * td;
                        }
                    }
                }
                #pragma unroll
                for (int ii = 0; ii < 4; ii++) acc[fr][fc][ii] = 0.f;
            }
        }

        __syncthreads();                      // all reads of wb (chunk c-1) done
        if (c < 7) {
            unsigned short* rowp = &wb[tr * 128];
            *(uint4*)&rowp[((tc * 2)     ^ (tr & 7)) * 8] = q0n;
            *(uint4*)&rowp[((tc * 2 + 1) ^ (tr & 7)) * 8] = q1n;
            float ss = ssn;
            ss += __shfl_xor(ss, 1); ss += __shfl_xor(ss, 2); ss += __shfl_xor(ss, 4);
            if (tc == 0) {
                ssy_s[(c + 1) * 64 + tr] = ss;
                if (xh == 0) lsum += 512.f * ss;
            }
        }
        __syncthreads();                      // chunk c+1 published
    }

    // -------- block reductions --------
    #pragma unroll
    for (int o = 32; o > 0; o >>= 1) lsum += __shfl_down(lsum, o, 64);
    if (lane == 0) red[wave] = lsum;
    __syncthreads();                          // also: all Ys reads complete

    if (xh == 0) {                            // block-uniform: barriers legal
        // reduce cs over tr within wave (lanes sharing tc differ in bits 3..5)
        #pragma unroll
        for (int j = 0; j < 16; ++j) {
            cs[j] += __shfl_xor(cs[j], 8);
            cs[j] += __shfl_xor(cs[j], 16);
            cs[j] += __shfl_xor(cs[j], 32);
        }
        float* scr = (float*)Ys;              // 8 x 128 f32 scratch
        if (lane < 8) {
            #pragma unroll
            for (int j = 0; j < 16; ++j) scr[wave * 128 + lane * 16 + j] = cs[j];
        }
        __syncthreads();
        if (t < 128) {
            float sc = 0.f;
            #pragma unroll
            for (int w = 0; w < 8; ++w) sc += scr[w * 128 + t];
            Scol[dist * 8192 + m * 128 + t] = sc;
        }
    }
    if (t == 0) {
        float s = 0.f;
        #pragma unroll
        for (int w = 0; w < 8; ++w) s += red[w];
        pslots[bx] = s;
    }
}

// Final reduction: 256 neg/ssq partials + closed-form pos dot:
//   total -= 2 * sum_m <S_A[m], S_C[m]>
__global__ __launch_bounds__(256) void reduce_kernel(
    const float* __restrict__ pslots, const float* __restrict__ Scol,
    float* __restrict__ out)
{
    const int t = threadIdx.x;
    float s = pslots[t];
    float dot = 0.f;
    #pragma unroll 8
    for (int k = 0; k < 32; ++k) {            // 8192 (m,d) pairs / 256 threads
        const int p = t + k * 256;
        dot += Scol[p] * Scol[8192 + p];
    }
    s -= 2.f * dot;
    #pragma unroll
    for (int o = 32; o > 0; o >>= 1) s += __shfl_down(s, o, 64);
    __shared__ float red[4];
    const int wave = t >> 6, lane = t & 63;
    if (lane == 0) red[wave] = s;
    __syncthreads();
    if (t == 0) out[0] = (red[0] + red[1] + red[2] + red[3]) * INV_COUNT;
}

extern "C" void kernel_launch(void* const* d_in, const int* in_sizes, int n_in,
                              void* d_out, int out_size, void* d_ws, size_t ws_size,
                              hipStream_t stream) {
    const float* mu    = (const float*)d_in[0];
    const float* sigma = (const float*)d_in[1];
    const float* epsA  = (const float*)d_in[2];
    const float* epsB  = (const float*)d_in[3];
    const float* epsC  = (const float*)d_in[4];
    float* out = (float*)d_out;

    float* pslots = (float*)d_ws;            // 256 f
    float* Scol   = pslots + 256;            // 2 x 64 x 128 f = 64 KB

    mono_kernel<<<NBLK, 512, 0, stream>>>(mu, sigma, epsA, epsB, epsC,
                                          pslots, Scol);

    reduce_kernel<<<1, 256, 0, stream>>>(pslots, Scol, out);
}

// Round 8
// 124.607 us; speedup vs baseline: 1.0422x; 1.0422x over previous
//
#include <hip/hip_runtime.h>

typedef short bf16x8 __attribute__((ext_vector_type(8)));
typedef float f32x4 __attribute__((ext_vector_type(4)));

#define D 128
#define NBLK 256                            // (dist 2) x (m 64) x (xh 2)
#define INV_COUNT 5.9604644775390625e-08f   // 1 / (64*512*512)

__device__ __forceinline__ unsigned short f2bf(float f) {
    unsigned u = __float_as_uint(f);
    u += 0x7FFFu + ((u >> 16) & 1u);        // round-to-nearest-even
    return (unsigned short)(u >> 16);
}
__device__ __forceinline__ float bf2f(unsigned short h) {
    return __uint_as_float(((unsigned)h) << 16);
}

// Convert 4 f32 (mu + sigma*eps) -> 2 packed bf16 words + ssq + colsum.
// cs4 indices are compile-time after inlining (register array stays in regs).
__device__ __forceinline__ void cvt4(float4 e, float4 u, float4 s,
                                     float* cs4, unsigned& lo, unsigned& hi,
                                     float& ss)
{
    unsigned short h0 = f2bf(fmaf(s.x, e.x, u.x));
    unsigned short h1 = f2bf(fmaf(s.y, e.y, u.y));
    unsigned short h2 = f2bf(fmaf(s.z, e.z, u.z));
    unsigned short h3 = f2bf(fmaf(s.w, e.w, u.w));
    float f0 = bf2f(h0), f1 = bf2f(h1), f2 = bf2f(h2), f3 = bf2f(h3);
    ss += f0 * f0 + f1 * f1 + f2 * f2 + f3 * f3;
    cs4[0] += f0; cs4[1] += f1; cs4[2] += f2; cs4[3] += f3;
    lo = (unsigned)h0 | ((unsigned)h1 << 16);
    hi = (unsigned)h2 | ((unsigned)h3 << 16);
}

// MONO kernel, R7 structure + MLP fixes:
//  - launch_bounds(512,2): grid gives 2 waves/SIMD; allow 256 VGPR (R7's 76
//    VGPR starved memory-level parallelism -> 650 GB/s latency-bound).
//  - x operand prepped per-lane DIRECTLY into aF registers (swizzle-cancel
//    algebra, HW-verified R3..R7): 48 independent float4 loads in one burst,
//    no LDS transit, no barriers.
//  - y-loop: T14 split. Phase A issues chunk c+1's 12 float4 loads into
//    named regs; MFMA+epilogue of chunk c touches only LDS/regs (no vmcnt
//    drain possible); phase B (after barrier) converts + publishes.
__global__ __launch_bounds__(512, 2) void mono_kernel(
    const float* __restrict__ mu, const float* __restrict__ sigma,
    const float* __restrict__ epsA, const float* __restrict__ epsB,
    const float* __restrict__ epsC,
    float* __restrict__ pslots, float* __restrict__ Scol)
{
    __shared__ unsigned short Ys[2][64 * 128];   // 32 KB y-stream dbuf
    __shared__ float ssx_s[256];
    __shared__ float ssy_s[512];
    __shared__ float red[8];

    const int bx = blockIdx.x;
    const int t  = threadIdx.x;
    const int wave = t >> 6, lane = t & 63;

    const int xcd = bx & 7;
    const int mh  = (bx >> 3) & 7;
    const int m   = xcd + mh * 8;             // m % 8 == xcd
    const int q   = bx >> 6;
    const int dist = q & 1;                   // 0 -> dBA (y=A), 1 -> dBC (y=C)
    const int xh   = q >> 1;                  // which 256-row half of X_B
    const int gy   = dist ? 2 : 0;

    const float* epsY = (dist ? epsC : epsA) + (size_t)m * 512 * D;
    const float* epsX = epsB + ((size_t)m * 512 + xh * 256) * D;
    const float* muY  = mu    + (size_t)gy * 512 * D;
    const float* sgY  = sigma + (size_t)gy * 512 * D;
    const float* muX  = mu    + (size_t)(512 + xh * 256) * D;
    const float* sgX  = sigma + (size_t)(512 + xh * 256) * D;

    const int tr = t >> 3;                    // row within 64-row chunk
    const int tc = t & 7;                     // 16-elem col segment
    const int coff = tc * 16;
    const int l15 = lane & 15, quad = lane >> 4;

    float cs[16];
    #pragma unroll
    for (int j = 0; j < 16; ++j) cs[j] = 0.f;
    float lsum = 0.f;

    // -------- x operand: per-lane direct prep into registers --------
    // lane (l15,quad) of wave w owns rows w*32 + fr*16 + l15, f32 elements
    // [(kk*4+quad)*8, +8)  == the MFMA A fragment (swizzle cancels).
    bf16x8 aF[4][2];
    float rss0 = 0.f, rss1 = 0.f;
    {
        const int rbase = wave * 32 + l15;
        #pragma unroll
        for (int fr = 0; fr < 2; fr++) {
            const size_t row = (size_t)(rbase + fr * 16);
            const float* er = epsX + row * D;
            const float* ur = muX  + row * D;
            const float* sr = sgX  + row * D;
            #pragma unroll
            for (int kk = 0; kk < 4; kk++) {
                const int e0 = (kk * 4 + quad) * 8;
                float4 ea = *(const float4*)(er + e0);
                float4 eb = *(const float4*)(er + e0 + 4);
                float4 ua = *(const float4*)(ur + e0);
                float4 ub = *(const float4*)(ur + e0 + 4);
                float4 sa = *(const float4*)(sr + e0);
                float4 sb = *(const float4*)(sr + e0 + 4);
                unsigned short h0 = f2bf(fmaf(sa.x, ea.x, ua.x));
                unsigned short h1 = f2bf(fmaf(sa.y, ea.y, ua.y));
                unsigned short h2 = f2bf(fmaf(sa.z, ea.z, ua.z));
                unsigned short h3 = f2bf(fmaf(sa.w, ea.w, ua.w));
                unsigned short h4 = f2bf(fmaf(sb.x, eb.x, ub.x));
                unsigned short h5 = f2bf(fmaf(sb.y, eb.y, ub.y));
                unsigned short h6 = f2bf(fmaf(sb.z, eb.z, ub.z));
                unsigned short h7 = f2bf(fmaf(sb.w, eb.w, ub.w));
                bf16x8 fg;
                fg[0] = (short)h0; fg[1] = (short)h1;
                fg[2] = (short)h2; fg[3] = (short)h3;
                fg[4] = (short)h4; fg[5] = (short)h5;
                fg[6] = (short)h6; fg[7] = (short)h7;
                aF[kk][fr] = fg;
                float f0 = bf2f(h0), f1 = bf2f(h1), f2 = bf2f(h2), f3 = bf2f(h3);
                float f4 = bf2f(h4), f5 = bf2f(h5), f6 = bf2f(h6), f7 = bf2f(h7);
                float ps = f0*f0 + f1*f1 + f2*f2 + f3*f3
                         + f4*f4 + f5*f5 + f6*f6 + f7*f7;
                if (fr == 0) rss0 += ps; else rss1 += ps;
            }
        }
    }
    // row sums: the 4 quads hold disjoint 32-elem partials of the same row
    rss0 += __shfl_xor(rss0, 16); rss0 += __shfl_xor(rss0, 32);
    rss1 += __shfl_xor(rss1, 16); rss1 += __shfl_xor(rss1, 32);
    if (quad == 0) {
        ssx_s[wave * 32 + l15]      = rss0;
        ssx_s[wave * 32 + 16 + l15] = rss1;
    }

    // -------- y chunk 0: full prep (load + convert + publish) --------
    {
        const float4* er = (const float4*)(epsY + (size_t)tr * D + coff);
        const float4* ur = (const float4*)(muY  + (size_t)tr * D + coff);
        const float4* sr = (const float4*)(sgY  + (size_t)tr * D + coff);
        float4 E0 = er[0], E1 = er[1], E2 = er[2], E3 = er[3];
        float4 U0 = ur[0], U1 = ur[1], U2 = ur[2], U3 = ur[3];
        float4 S0 = sr[0], S1 = sr[1], S2 = sr[2], S3 = sr[3];
        uint4 q0, q1; float ss = 0.f;
        cvt4(E0, U0, S0, &cs[0],  q0.x, q0.y, ss);
        cvt4(E1, U1, S1, &cs[4],  q0.z, q0.w, ss);
        cvt4(E2, U2, S2, &cs[8],  q1.x, q1.y, ss);
        cvt4(E3, U3, S3, &cs[12], q1.z, q1.w, ss);
        unsigned short* rowp = &Ys[0][tr * 128];
        *(uint4*)&rowp[((tc * 2)     ^ (tr & 7)) * 8] = q0;
        *(uint4*)&rowp[((tc * 2 + 1) ^ (tr & 7)) * 8] = q1;
        ss += __shfl_xor(ss, 1); ss += __shfl_xor(ss, 2); ss += __shfl_xor(ss, 4);
        if (tc == 0) { ssy_s[tr] = ss; if (xh == 0) lsum += 512.f * ss; }
    }
    __syncthreads();

    f32x4 acc[2][4] = {};

    // -------- main loop: 8 chunks of 64 y rows --------
    #pragma unroll 1
    for (int c = 0; c < 8; ++c) {
        const unsigned short* bb = (c & 1) ? Ys[1] : Ys[0];
        unsigned short*       wb = (c & 1) ? Ys[0] : Ys[1];

        // phase A: ISSUE chunk c+1 loads (named regs, no converts -> 12 deep)
        float4 E0, E1, E2, E3, U0, U1, U2, U3, S0, S1, S2, S3;
        if (c < 7) {
            const size_t n = (size_t)((c + 1) * 64 + tr);
            const float4* er = (const float4*)(epsY + n * D + coff);
            const float4* ur = (const float4*)(muY  + n * D + coff);
            const float4* sr = (const float4*)(sgY  + n * D + coff);
            E0 = er[0]; E1 = er[1]; E2 = er[2]; E3 = er[3];
            U0 = ur[0]; U1 = ur[1]; U2 = ur[2]; U3 = ur[3];
            S0 = sr[0]; S1 = sr[1]; S2 = sr[2]; S3 = sr[3];
        }

        // MFMA on chunk c (LDS + regs only; vmem loads stay in flight)
        #pragma unroll
        for (int kk = 0; kk < 4; kk++) {
            bf16x8 bfr[4];
            #pragma unroll
            for (int fc = 0; fc < 4; fc++) {
                const int row = fc * 16 + l15;
                bfr[fc] = *(const bf16x8*)&bb[row * 128 +
                            (((kk * 4 + quad) ^ (row & 7)) * 8)];
            }
            #pragma unroll
            for (int fr = 0; fr < 2; fr++)
                #pragma unroll
                for (int fc = 0; fc < 4; fc++)
                    acc[fr][fc] = __builtin_amdgcn_mfma_f32_16x16x32_bf16(
                        aF[kk][fr], bfr[fc], acc[fr][fc], 0, 0, 0);
        }

        // epilogue chunk c; C layout: col=lane&15, row=quad*4+ii
        #pragma unroll
        for (int fc = 0; fc < 4; fc++) {
            float y2 = ssy_s[c * 64 + fc * 16 + l15];
            #pragma unroll
            for (int fr = 0; fr < 2; fr++) {
                float d2v[4];
                #pragma unroll
                for (int ii = 0; ii < 4; ii++) {
                    float x2 = ssx_s[wave * 32 + fr * 16 + quad * 4 + ii];
                    d2v[ii] = fmaf(-2.f, acc[fr][fc][ii], x2 + y2);
                }
                float mn = fminf(fminf(d2v[0], d2v[1]), fminf(d2v[2], d2v[3]));
                if (__any(mn < 4.f)) {        // relu(M-d) nonzero is rare
                    #pragma unroll
                    for (int ii = 0; ii < 4; ii++) {
                        if (d2v[ii] < 4.f) {
                            float td = 2.f - sqrtf(fmaxf(d2v[ii], 1e-12f));
                            lsum += td * td;
                        }
                    }
                }
                #pragma unroll
                for (int ii = 0; ii < 4; ii++) acc[fr][fc][ii] = 0.f;
            }
        }

        __syncthreads();                      // bb reads done; wb free

        // phase B: convert + publish chunk c+1 (vmcnt waits land here)
        if (c < 7) {
            uint4 q0n, q1n; float ssn = 0.f;
            cvt4(E0, U0, S0, &cs[0],  q0n.x, q0n.y, ssn);
            cvt4(E1, U1, S1, &cs[4],  q0n.z, q0n.w, ssn);
            cvt4(E2, U2, S2, &cs[8],  q1n.x, q1n.y, ssn);
            cvt4(E3, U3, S3, &cs[12], q1n.z, q1n.w, ssn);
            unsigned short* rowp = &wb[tr * 128];
            *(uint4*)&rowp[((tc * 2)     ^ (tr & 7)) * 8] = q0n;
            *(uint4*)&rowp[((tc * 2 + 1) ^ (tr & 7)) * 8] = q1n;
            float ss = ssn;
            ss += __shfl_xor(ss, 1); ss += __shfl_xor(ss, 2); ss += __shfl_xor(ss, 4);
            if (tc == 0) {
                ssy_s[(c + 1) * 64 + tr] = ss;
                if (xh == 0) lsum += 512.f * ss;
            }
        }
        __syncthreads();                      // chunk c+1 published
    }

    // -------- block reductions --------
    #pragma unroll
    for (int o = 32; o > 0; o >>= 1) lsum += __shfl_down(lsum, o, 64);
    if (lane == 0) red[wave] = lsum;
    __syncthreads();                          // all Ys reads complete

    if (xh == 0) {                            // block-uniform: barriers legal
        #pragma unroll
        for (int j = 0; j < 16; ++j) {        // reduce over rows (lane bits 3..5)
            cs[j] += __shfl_xor(cs[j], 8);
            cs[j] += __shfl_xor(cs[j], 16);
            cs[j] += __shfl_xor(cs[j], 32);
        }
        float* scr = (float*)Ys;              // 8 x 128 f32 scratch
        if (lane < 8) {
            #pragma unroll
            for (int j = 0; j < 16; ++j) scr[wave * 128 + lane * 16 + j] = cs[j];
        }
        __syncthreads();
        if (t < 128) {
            float sc = 0.f;
            #pragma unroll
            for (int w = 0; w < 8; ++w) sc += scr[w * 128 + t];
            Scol[dist * 8192 + m * 128 + t] = sc;
        }
    }
    if (t == 0) {
        float s = 0.f;
        #pragma unroll
        for (int w = 0; w < 8; ++w) s += red[w];
        pslots[bx] = s;
    }
}

// Final reduction: 256 neg/ssq partials + closed-form pos dot:
//   total -= 2 * sum_m <S_A[m], S_C[m]>
__global__ __launch_bounds__(256) void reduce_kernel(
    const float* __restrict__ pslots, const float* __restrict__ Scol,
    float* __restrict__ out)
{
    const int t = threadIdx.x;
    float s = pslots[t];
    float dot = 0.f;
    #pragma unroll 8
    for (int k = 0; k < 32; ++k) {            // 8192 (m,d) pairs / 256 threads
        const int p = t + k * 256;
        dot += Scol[p] * Scol[8192 + p];
    }
    s -= 2.f * dot;
    #pragma unroll
    for (int o = 32; o > 0; o >>= 1) s += __shfl_down(s, o, 64);
    __shared__ float red[4];
    const int wave = t >> 6, lane = t & 63;
    if (lane == 0) red[wave] = s;
    __syncthreads();
    if (t == 0) out[0] = (red[0] + red[1] + red[2] + red[3]) * INV_COUNT;
}

extern "C" void kernel_launch(void* const* d_in, const int* in_sizes, int n_in,
                              void* d_out, int out_size, void* d_ws, size_t ws_size,
                              hipStream_t stream) {
    const float* mu    = (const float*)d_in[0];
    const float* sigma = (const float*)d_in[1];
    const float* epsA  = (const float*)d_in[2];
    const float* epsB  = (const float*)d_in[3];
    const float* epsC  = (const float*)d_in[4];
    float* out = (float*)d_out;

    float* pslots = (float*)d_ws;            // 256 f
    float* Scol   = pslots + 256;            // 2 x 64 x 128 f = 64 KB

    mono_kernel<<<NBLK, 512, 0, stream>>>(mu, sigma, epsA, epsB, epsC,
                                          pslots, Scol);

    reduce_kernel<<<1, 256, 0, stream>>>(pslots, Scol, out);
}

// Round 9
// 121.370 us; speedup vs baseline: 1.0700x; 1.0267x over previous
//
#include <hip/hip_runtime.h>

typedef short bf16x8 __attribute__((ext_vector_type(8)));
typedef float f32x4 __attribute__((ext_vector_type(4)));

#define D 128
#define NBLK 256                            // (dist 2) x (m 64) x (xh 2)
#define INV_COUNT 5.9604644775390625e-08f   // 1 / (64*512*512)

__device__ __forceinline__ unsigned short f2bf(float f) {
    unsigned u = __float_as_uint(f);
    u += 0x7FFFu + ((u >> 16) & 1u);        // round-to-nearest-even
    return (unsigned short)(u >> 16);
}
__device__ __forceinline__ float bf2f(unsigned short h) {
    return __uint_as_float(((unsigned)h) << 16);
}

// 12 lane-contiguous loads: instr (array, j) covers bytes [base + j*1024,
// +1024) of the chunk -> 16 cache lines per wave-instr (was 64 at the old
// stride-64B mapping: the R0-R8 transaction-fragmentation bottleneck).
// Thread gets float4 of row (R0 + wave*8 + j*2 + (lane>>5)) at float col
// (lane&31)*4.
__device__ __forceinline__ void load12(const float* ep, const float* up,
                                       const float* sp, int R0, int wave,
                                       int rl, int c5,
                                       float4 E[4], float4 U[4], float4 S[4])
{
    #pragma unroll
    for (int j = 0; j < 4; ++j) {
        const size_t off = (size_t)(R0 + wave * 8 + j * 2 + rl) * D + c5 * 4;
        E[j] = *(const float4*)(ep + off);
        U[j] = *(const float4*)(up + off);
        S[j] = *(const float4*)(sp + off);
    }
}

__device__ __forceinline__ void cvtpk(float4 e, float4 u, float4 s,
                                      unsigned long long& pk, float& ss,
                                      float fv[4])
{
    unsigned short h0 = f2bf(fmaf(s.x, e.x, u.x));
    unsigned short h1 = f2bf(fmaf(s.y, e.y, u.y));
    unsigned short h2 = f2bf(fmaf(s.z, e.z, u.z));
    unsigned short h3 = f2bf(fmaf(s.w, e.w, u.w));
    float f0 = bf2f(h0), f1 = bf2f(h1), f2 = bf2f(h2), f3 = bf2f(h3);
    ss = f0 * f0 + f1 * f1 + f2 * f2 + f3 * f3;
    fv[0] = f0; fv[1] = f1; fv[2] = f2; fv[3] = f3;
    pk = (unsigned long long)((unsigned)h0 | ((unsigned)h1 << 16)) |
         ((unsigned long long)((unsigned)h2 | ((unsigned)h3 << 16)) << 32);
}

// Convert + publish one 64-row chunk held in E/U/S. Writes the SAME swizzled
// LDS image as R7/R8 (granule g at slot g^(r&7); 8B halves) -> MFMA read
// path unchanged (HW-verified). Row-sumsq via 5x shfl_xor over lane&31.
#define CVTWR(Ebuf, Ubuf, Sbuf, BUF, SSROW, FOLD, DOCS)                        \
    do {                                                                       \
        _Pragma("unroll")                                                      \
        for (int j = 0; j < 4; ++j) {                                          \
            unsigned long long pk; float ss; float fv[4];                      \
            cvtpk(Ebuf[j], Ubuf[j], Sbuf[j], pk, ss, fv);                      \
            if (DOCS) {                                                        \
                cs[0] += fv[0]; cs[1] += fv[1];                                \
                cs[2] += fv[2]; cs[3] += fv[3];                                \
            }                                                                  \
            const int r = wave * 8 + j * 2 + rl;                               \
            ((unsigned long long*)&(BUF)[r * 128])                             \
                [((g16 ^ (r & 7)) << 1) | half] = pk;                          \
            ss += __shfl_xor(ss, 1);  ss += __shfl_xor(ss, 2);                 \
            ss += __shfl_xor(ss, 4);  ss += __shfl_xor(ss, 8);                 \
            ss += __shfl_xor(ss, 16);                                          \
            if (c5 == 0) {                                                     \
                (SSROW)[r] = ss;                                               \
                if (FOLD) lsum += 512.f * ss;                                  \
            }                                                                  \
        }                                                                      \
    } while (0)

__global__ __launch_bounds__(512, 2) void mono_kernel(
    const float* __restrict__ mu, const float* __restrict__ sigma,
    const float* __restrict__ epsA, const float* __restrict__ epsB,
    const float* __restrict__ epsC,
    float* __restrict__ pslots, float* __restrict__ Scol)
{
    __shared__ unsigned short Ys[2][64 * 128];   // 32 KB dbuf
    __shared__ float ssx_s[256];
    __shared__ float ssy_s[512];
    __shared__ float red[8];

    const int bx = blockIdx.x;
    const int t  = threadIdx.x;
    const int wave = t >> 6, lane = t & 63;

    const int xcd = bx & 7;
    const int mh  = (bx >> 3) & 7;
    const int m   = xcd + mh * 8;             // m % 8 == xcd
    const int q   = bx >> 6;
    const int dist = q & 1;                   // 0 -> dBA (y=A), 1 -> dBC (y=C)
    const int xh   = q >> 1;                  // which 256-row half of X_B
    const int gy   = dist ? 2 : 0;

    const float* epsY = (dist ? epsC : epsA) + (size_t)m * 512 * D;
    const float* epsX = epsB + ((size_t)m * 512 + xh * 256) * D;
    const float* muY  = mu    + (size_t)gy * 512 * D;
    const float* sgY  = sigma + (size_t)gy * 512 * D;
    const float* muX  = mu    + (size_t)(512 + xh * 256) * D;
    const float* sgX  = sigma + (size_t)(512 + xh * 256) * D;

    const int rl = lane >> 5;                 // row parity within instr
    const int c5 = lane & 31;                 // column lane
    const int g16 = c5 >> 1, half = c5 & 1;   // 16B granule / 8B half
    const int l15 = lane & 15, quad = lane >> 4;

    float cs[4] = {0.f, 0.f, 0.f, 0.f};
    float lsum = 0.f;
    const bool fold = (xh == 0);

    float4 E[4], U[4], S[4];

    // -------- x operand: 4 coalesced chunks through Ys[0] -> aF regs ------
    bf16x8 aF[4][2];
    load12(epsX, muX, sgX, 0, wave, rl, c5, E, U, S);
    #pragma unroll 1
    for (int p = 0; p < 4; ++p) {
        CVTWR(E, U, S, Ys[0], ssx_s + p * 64, false, false);
        if (p < 3) load12(epsX, muX, sgX, (p + 1) * 64, wave, rl, c5, E, U, S);
        __syncthreads();
        if ((wave >> 1) == p) {               // waves 2p,2p+1 own these rows
            #pragma unroll
            for (int kk = 0; kk < 4; kk++)
                #pragma unroll
                for (int fr = 0; fr < 2; fr++) {
                    const int row = (wave & 1) * 32 + fr * 16 + l15;
                    aF[kk][fr] = *(const bf16x8*)&Ys[0][row * 128 +
                                  (((kk * 4 + quad) ^ (row & 7)) * 8)];
                }
        }
        __syncthreads();
    }

    // -------- y chunk 0 --------
    load12(epsY, muY, sgY, 0, wave, rl, c5, E, U, S);
    CVTWR(E, U, S, Ys[0], ssy_s, fold, true);
    __syncthreads();

    f32x4 acc[2][4] = {};

    // -------- main loop: 8 chunks of 64 y rows --------
    #pragma unroll 1
    for (int c = 0; c < 8; ++c) {
        const unsigned short* bb = (c & 1) ? Ys[1] : Ys[0];
        unsigned short*       wb = (c & 1) ? Ys[0] : Ys[1];

        // phase A: issue chunk c+1 loads (regs only; overlap MFMA below)
        if (c < 7) load12(epsY, muY, sgY, (c + 1) * 64, wave, rl, c5, E, U, S);

        // MFMA on chunk c
        #pragma unroll
        for (int kk = 0; kk < 4; kk++) {
            bf16x8 bfr[4];
            #pragma unroll
            for (int fc = 0; fc < 4; fc++) {
                const int row = fc * 16 + l15;
                bfr[fc] = *(const bf16x8*)&bb[row * 128 +
                            (((kk * 4 + quad) ^ (row & 7)) * 8)];
            }
            #pragma unroll
            for (int fr = 0; fr < 2; fr++)
                #pragma unroll
                for (int fc = 0; fc < 4; fc++)
                    acc[fr][fc] = __builtin_amdgcn_mfma_f32_16x16x32_bf16(
                        aF[kk][fr], bfr[fc], acc[fr][fc], 0, 0, 0);
        }

        // epilogue chunk c; C layout: col=lane&15, row=quad*4+ii
        #pragma unroll
        for (int fc = 0; fc < 4; fc++) {
            float y2 = ssy_s[c * 64 + fc * 16 + l15];
            #pragma unroll
            for (int fr = 0; fr < 2; fr++) {
                float d2v[4];
                #pragma unroll
                for (int ii = 0; ii < 4; ii++) {
                    float x2 = ssx_s[wave * 32 + fr * 16 + quad * 4 + ii];
                    d2v[ii] = fmaf(-2.f, acc[fr][fc][ii], x2 + y2);
                }
                float mn = fminf(fminf(d2v[0], d2v[1]), fminf(d2v[2], d2v[3]));
                if (__any(mn < 4.f)) {        // relu(M-d) nonzero is rare
                    #pragma unroll
                    for (int ii = 0; ii < 4; ii++) {
                        if (d2v[ii] < 4.f) {
                            float td = 2.f - sqrtf(fmaxf(d2v[ii], 1e-12f));
                            lsum += td * td;
                        }
                    }
                }
                #pragma unroll
                for (int ii = 0; ii < 4; ii++) acc[fr][fc][ii] = 0.f;
            }
        }

        __syncthreads();                      // bb reads done; wb free

        // phase B: convert + publish chunk c+1 (vmcnt waits land here)
        if (c < 7) CVTWR(E, U, S, wb, ssy_s + (c + 1) * 64, fold, true);
        __syncthreads();                      // chunk c+1 published
    }

    // -------- block reductions --------
    #pragma unroll
    for (int o = 32; o > 0; o >>= 1) lsum += __shfl_down(lsum, o, 64);
    if (lane == 0) red[wave] = lsum;
    __syncthreads();                          // all Ys reads complete

    if (xh == 0) {                            // block-uniform: barriers legal
        #pragma unroll
        for (int jj = 0; jj < 4; ++jj) cs[jj] += __shfl_xor(cs[jj], 32);
        float* scr = (float*)Ys;              // 8 x 128 f32 scratch
        if (lane < 32) {
            #pragma unroll
            for (int jj = 0; jj < 4; ++jj)
                scr[wave * 128 + c5 * 4 + jj] = cs[jj];
        }
        __syncthreads();
        if (t < 128) {
            float sc = 0.f;
            #pragma unroll
            for (int w = 0; w < 8; ++w) sc += scr[w * 128 + t];
            Scol[dist * 8192 + m * 128 + t] = sc;
        }
    }
    if (t == 0) {
        float s = 0.f;
        #pragma unroll
        for (int w = 0; w < 8; ++w) s += red[w];
        pslots[bx] = s;
    }
}

// Final reduction: 256 neg/ssq partials + closed-form pos dot:
//   total -= 2 * sum_m <S_A[m], S_C[m]>
__global__ __launch_bounds__(256) void reduce_kernel(
    const float* __restrict__ pslots, const float* __restrict__ Scol,
    float* __restrict__ out)
{
    const int t = threadIdx.x;
    float s = pslots[t];
    float dot = 0.f;
    #pragma unroll 8
    for (int k = 0; k < 32; ++k) {            // 8192 (m,d) pairs / 256 threads
        const int p = t + k * 256;
        dot += Scol[p] * Scol[8192 + p];
    }
    s -= 2.f * dot;
    #pragma unroll
    for (int o = 32; o > 0; o >>= 1) s += __shfl_down(s, o, 64);
    __shared__ float red[4];
    const int wave = t >> 6, lane = t & 63;
    if (lane == 0) red[wave] = s;
    __syncthreads();
    if (t == 0) out[0] = (red[0] + red[1] + red[2] + red[3]) * INV_COUNT;
}

extern "C" void kernel_launch(void* const* d_in, const int* in_sizes, int n_in,
                              void* d_out, int out_size, void* d_ws, size_t ws_size,
                              hipStream_t stream) {
    const float* mu    = (const float*)d_in[0];
    const float* sigma = (const float*)d_in[1];
    const float* epsA  = (const float*)d_in[2];
    const float* epsB  = (const float*)d_in[3];
    const float* epsC  = (const float*)d_in[4];
    float* out = (float*)d_out;

    float* pslots = (float*)d_ws;            // 256 f
    float* Scol   = pslots + 256;            // 2 x 64 x 128 f = 64 KB

    mono_kernel<<<NBLK, 512, 0, stream>>>(mu, sigma, epsA, epsB, epsC,
                                          pslots, Scol);

    reduce_kernel<<<1, 256, 0, stream>>>(pslots, Scol, out);
}